// Round 13
// baseline (363.243 us; speedup 1.0000x reference)
//
#include <hip/hip_runtime.h>
#include <hip/hip_fp16.h>
#include <math.h>

#define N_NODES 150000
#define D 64
#define NEDGE 4800000
#define NUM_LAYERS 3

#define BSHIFT 8
#define NBUCKET 586      // ceil(150000/256)
#define NBPAD 768        // 3*256 padded scan width
#define BINTILE 8192
#define NBIN_BLOCKS 586  // ceil(NEDGE/BINTILE)
#define BINCAP 8960      // fixed bin bucket capacity: mean 8192 + 8.5 sigma(90)
#define ECAP 10752       // fixed ewf bucket capacity: BINCAP + 256*7 pad bound
#define SCAP 9216        // sortpass2 LDS staging (len <= BINCAP < SCAP)
#define ZROW 150000u     // dummy src pointing at a zeroed row

typedef float vf4 __attribute__((ext_vector_type(4)));
typedef unsigned vu4 __attribute__((ext_vector_type(4)));

// ---- init fixed bucket cursors ----
__global__ void binit(int* __restrict__ bcur16) {
    int i = blockIdx.x * blockDim.x + threadIdx.x;
    if (i < NBPAD) bcur16[i * 16] = i * BINCAP;
}

// ---- pass 1: bucket-sort edges; LDS-staged records, per-thread ordered run write-out ----
__global__ void __launch_bounds__(256) binpass2(const int* __restrict__ row,
                                                const int* __restrict__ col,
                                                int* __restrict__ bcur16,
                                                unsigned* __restrict__ bin) {
    __shared__ unsigned srec[BINTILE];  // 32 KB, bucket-sorted records
    __shared__ int hist[NBPAD];
    __shared__ int lscan[NBPAD];
    __shared__ int lcur[NBPAD];
    __shared__ int gbase[NBPAD];
    __shared__ int tsum[256];
    int t = threadIdx.x;
    int base = blockIdx.x * BINTILE;
    int n = NEDGE - base;
    if (n > BINTILE) n = BINTILE;
    for (int i = t; i < NBPAD; i += 256) hist[i] = 0;
    __syncthreads();
    for (int i = t; i < n; i += 256)
        atomicAdd(&hist[col[base + i] >> BSHIFT], 1);
    __syncthreads();
    int b0 = t * 3;
    int l0 = hist[b0], l1 = hist[b0 + 1], l2 = hist[b0 + 2];
    tsum[t] = l0 + l1 + l2;
    __syncthreads();
    for (int ofs = 1; ofs < 256; ofs <<= 1) {
        int xv = (t >= ofs) ? tsum[t - ofs] : 0;
        __syncthreads();
        tsum[t] += xv;
        __syncthreads();
    }
    int run = (t > 0) ? tsum[t - 1] : 0;
    lscan[b0] = run; lcur[b0] = run;
    lscan[b0 + 1] = run + l0; lcur[b0 + 1] = run + l0;
    lscan[b0 + 2] = run + l0 + l1; lcur[b0 + 2] = run + l0 + l1;
    gbase[b0]     = l0 ? atomicAdd(&bcur16[b0 * 16], l0) : 0;
    gbase[b0 + 1] = l1 ? atomicAdd(&bcur16[(b0 + 1) * 16], l1) : 0;
    gbase[b0 + 2] = l2 ? atomicAdd(&bcur16[(b0 + 2) * 16], l2) : 0;
    __syncthreads();
    // stage records bucket-sorted in LDS (second global read of col)
    for (int i = t; i < n; i += 256) {
        int c = col[base + i];
        int r = row[base + i];
        int b = c >> BSHIFT;
        int pos = atomicAdd(&lcur[b], 1);
        srec[pos] = (unsigned)r | ((unsigned)(c & 255) << 18);
    }
    __syncthreads();
    // write-out: thread t copies its 3 buckets' runs contiguously
#pragma unroll
    for (int k = 0; k < 3; k++) {
        int b = b0 + k;
        int s = lscan[b], e2 = lcur[b], gb = gbase[b];
        for (int j = s; j < e2; j++) bin[gb + (j - s)] = srec[j];
    }
}

// ---- pass 2: within-bucket node sort + deg/dis/off2 + pad-to-8 lists + fused cvt ----
__global__ void __launch_bounds__(256) sortpass2(const unsigned* __restrict__ bin,
                                                 const int* __restrict__ bcur16,
                                                 const float4* __restrict__ x4,
                                                 float* __restrict__ dis,
                                                 int2* __restrict__ off2,
                                                 unsigned* __restrict__ ewf,
                                                 uint2* __restrict__ g0) {
    __shared__ unsigned srec[SCAP];
    __shared__ int hist[256];
    __shared__ int sc[256];
    __shared__ int ncur[256];
    __shared__ float sdis[256];
    int b = blockIdx.x, t = threadIdx.x;
    int s = b * BINCAP;
    int e = bcur16[b * 16];
    int len = e - s;
    int nst = len < SCAP ? len : SCAP;  // always fits (len <= BINCAP)
    for (int i = t; i < nst; i += 256) srec[i] = bin[s + i];
    hist[t] = 0;
    __syncthreads();
    for (int i = t; i < nst; i += 256)
        atomicAdd(&hist[srec[i] >> 18], 1);
    for (int i = nst + t; i < len; i += 256)
        atomicAdd(&hist[bin[s + i] >> 18], 1);
    __syncthreads();
    int val = hist[t];
    int lp = (val + 7) & ~7;  // padded list length (multiple of 8)
    sc[t] = lp;
    __syncthreads();
    for (int ofs = 1; ofs < 256; ofs <<= 1) {
        int xv = (t >= ofs) ? sc[t - ofs] : 0;
        __syncthreads();
        sc[t] += xv;
        __syncthreads();
    }
    int ex = sc[t] - lp;  // exclusive scan of padded lengths
    ncur[t] = ex;
    int ebase = b * ECAP;
    int node = (b << BSHIFT) + t;
    float w = (val > 0) ? (1.0f / sqrtf((float)val)) : 0.0f;
    if (node < N_NODES) {
        dis[node] = w;
        off2[node] = make_int2(ebase + ex, ebase + ex + lp);
    }
    sdis[t] = w;
    __syncthreads();
    for (int i = t; i < nst; i += 256) {
        unsigned rec = srec[i];
        int c = (int)(rec >> 18);
        int pos = ebase + atomicAdd(&ncur[c], 1);
        ewf[pos] = rec & 0x3FFFFu;
    }
    for (int i = nst + t; i < len; i += 256) {
        unsigned rec = bin[s + i];
        int c = (int)(rec >> 18);
        int pos = ebase + atomicAdd(&ncur[c], 1);
        ewf[pos] = rec & 0x3FFFFu;
    }
    // pad fill: disjoint addresses from scatter -> no sync needed
    for (int j = val; j < lp; ++j) ewf[ebase + ex + j] = ZROW;
    // fused cvt: g0 = dis * x (fp16) for this block's 256 nodes (coalesced)
    int gb16 = (b << 8) * 16;
    for (int i = t; i < 4096; i += 256) {
        int nl = i >> 4;
        int gnode = (b << 8) + nl;
        if (gnode >= N_NODES) continue;
        float wv = sdis[nl];
        float4 v = x4[gb16 + i];
        __half2 ha = __floats2half2_rn(wv * v.x, wv * v.y);
        __half2 hb = __floats2half2_rn(wv * v.z, wv * v.w);
        uint2 r;
        r.x = *reinterpret_cast<unsigned*>(&ha);
        r.y = *reinterpret_cast<unsigned*>(&hb);
        g0[gb16 + i] = r;
    }
}

// ---- propagation layer: wave64 handles TWO nodes (2 independent gather chains) ----
// R11 structure (proven 85.5us); ewf read with nontemporal hint (single-use stream).
template <bool FINAL>
__global__ void layer8(const char* __restrict__ hbase, const int2* __restrict__ off2,
                       const unsigned* __restrict__ ewf, const float* __restrict__ dis,
                       char* __restrict__ hout, const char* __restrict__ hA,
                       const char* __restrict__ hB, float* __restrict__ outf,
                       float alpha) {
    int wv = (blockIdx.x * blockDim.x + threadIdx.x) >> 6;
    int wid0 = wv << 1;
    if (wid0 >= N_NODES) return;
    int wid1 = wid0 | 1;  // N_NODES even -> always valid
    unsigned lane = threadIdx.x & 63u;
    unsigned g = lane >> 3;
    unsigned sub16 = (lane & 7u) << 4;
    int2 se0 = off2[wid0];
    int2 se1 = off2[wid1];
    int L0 = (se0.y - se0.x) >> 3;
    int L1 = (se1.y - se1.x) >> 3;
    int p0 = se0.x + (int)g * L0;
    int p1 = se1.x + (int)g * L1;

    float a0 = 0.f, a1 = 0.f, a2 = 0.f, a3 = 0.f;
    float a4 = 0.f, a5 = 0.f, a6 = 0.f, a7 = 0.f;
    float b0 = 0.f, b1 = 0.f, b2 = 0.f, b3 = 0.f;
    float b4 = 0.f, b5 = 0.f, b6 = 0.f, b7 = 0.f;

    auto ROW = [&](unsigned r) {
        return *reinterpret_cast<const uint4*>(hbase + ((r << 7) | sub16));
    };
    auto EW = [&](int idx) { return __builtin_nontemporal_load(&ewf[idx]); };
#define ACCD(d, aL, aH)                                                          \
    asm("v_fma_mix_f32 %0, %2, 1.0, %0 op_sel:[0,0,0] op_sel_hi:[1,0,0]\n\t"     \
        "v_fma_mix_f32 %1, %2, 1.0, %1 op_sel:[1,0,0] op_sel_hi:[1,0,0]"         \
        : "+v"(aL), "+v"(aH) : "v"(d))
#define ACCVA(v)               \
    do {                       \
        ACCD((v).x, a0, a1);   \
        ACCD((v).y, a2, a3);   \
        ACCD((v).z, a4, a5);   \
        ACCD((v).w, a6, a7);   \
    } while (0)
#define ACCVB(v)               \
    do {                       \
        ACCD((v).x, b0, b1);   \
        ACCD((v).y, b2, b3);   \
        ACCD((v).z, b4, b5);   \
        ACCD((v).w, b6, b7);   \
    } while (0)

    int m = (L0 < L1) ? L0 : L1;
    int k = 0;
    for (; k + 1 < m; k += 2) {  // 4 gathers in flight across 2 chains
        unsigned r00 = EW(p0 + k), r01 = EW(p0 + k + 1);
        unsigned r10 = EW(p1 + k), r11 = EW(p1 + k + 1);
        uint4 v00 = ROW(r00), v10 = ROW(r10), v01 = ROW(r01), v11 = ROW(r11);
        ACCVA(v00); ACCVB(v10); ACCVA(v01); ACCVB(v11);
    }
    int k0 = k, k1 = k;
    for (; k0 < L0; ++k0) { uint4 v = ROW(EW(p0 + k0)); ACCVA(v); }
    for (; k1 < L1; ++k1) { uint4 v = ROW(EW(p1 + k1)); ACCVB(v); }
#undef ACCVA
#undef ACCVB
#undef ACCD

    // reduce the 8 lane-groups (lanes sharing sub)
#pragma unroll
    for (int mm = 8; mm <= 32; mm <<= 1) {
        a0 += __shfl_xor(a0, mm, 64); a1 += __shfl_xor(a1, mm, 64);
        a2 += __shfl_xor(a2, mm, 64); a3 += __shfl_xor(a3, mm, 64);
        a4 += __shfl_xor(a4, mm, 64); a5 += __shfl_xor(a5, mm, 64);
        a6 += __shfl_xor(a6, mm, 64); a7 += __shfl_xor(a7, mm, 64);
        b0 += __shfl_xor(b0, mm, 64); b1 += __shfl_xor(b1, mm, 64);
        b2 += __shfl_xor(b2, mm, 64); b3 += __shfl_xor(b3, mm, 64);
        b4 += __shfl_xor(b4, mm, 64); b5 += __shfl_xor(b5, mm, 64);
        b6 += __shfl_xor(b6, mm, 64); b7 += __shfl_xor(b7, mm, 64);
    }

    if (g >= 2) return;
    int wid = (g == 0) ? wid0 : wid1;
    float s0 = g ? b0 : a0, s1 = g ? b1 : a1, s2 = g ? b2 : a2, s3 = g ? b3 : a3;
    float s4 = g ? b4 : a4, s5 = g ? b5 : a5, s6 = g ? b6 : a6, s7 = g ? b7 : a7;
    float w = dis[wid];
    unsigned ro = ((unsigned)wid << 7) | sub16;
    if (FINAL) {
        float inv = (w > 0.f) ? 1.0f / w : 0.f;
        uint4 a = *reinterpret_cast<const uint4*>(hA + ro);
        uint4 b = *reinterpret_cast<const uint4*>(hB + ro);
        const __half2* pa = reinterpret_cast<const __half2*>(&a);
        const __half2* pb = reinterpret_cast<const __half2*>(&b);
        float2 f0 = __half22float2(pa[0]), f1 = __half22float2(pa[1]);
        float2 f2 = __half22float2(pa[2]), f3 = __half22float2(pa[3]);
        float2 q0 = __half22float2(pb[0]), q1 = __half22float2(pb[1]);
        float2 q2 = __half22float2(pb[2]), q3 = __half22float2(pb[3]);
        vf4 o0 = {alpha * (inv * (f0.x + q0.x) + w * s0),
                  alpha * (inv * (f0.y + q0.y) + w * s1),
                  alpha * (inv * (f1.x + q1.x) + w * s2),
                  alpha * (inv * (f1.y + q1.y) + w * s3)};
        vf4 o1 = {alpha * (inv * (f2.x + q2.x) + w * s4),
                  alpha * (inv * (f2.y + q2.y) + w * s5),
                  alpha * (inv * (f3.x + q3.x) + w * s6),
                  alpha * (inv * (f3.y + q3.y) + w * s7)};
        unsigned sub = (lane & 7u);
        vf4* dst = reinterpret_cast<vf4*>(outf + (size_t)wid * 64 + sub * 8);
        __builtin_nontemporal_store(o0, dst);
        __builtin_nontemporal_store(o1, dst + 1);
    } else {
        float w2 = w * w;  // g_next = dis^2 * S
        __half2 q0 = __floats2half2_rn(w2 * s0, w2 * s1);
        __half2 q1 = __floats2half2_rn(w2 * s2, w2 * s3);
        __half2 q2 = __floats2half2_rn(w2 * s4, w2 * s5);
        __half2 q3 = __floats2half2_rn(w2 * s6, w2 * s7);
        vu4 st;
        st.x = *reinterpret_cast<unsigned*>(&q0);
        st.y = *reinterpret_cast<unsigned*>(&q1);
        st.z = *reinterpret_cast<unsigned*>(&q2);
        st.w = *reinterpret_cast<unsigned*>(&q3);
        __builtin_nontemporal_store(st, reinterpret_cast<vu4*>(hout + ro));
    }
}

extern "C" void kernel_launch(void* const* d_in, const int* in_sizes, int n_in,
                              void* d_out, int out_size, void* d_ws, size_t ws_size,
                              hipStream_t stream) {
    const float* x = (const float*)d_in[0];
    const int* edges = (const int*)d_in[1];
    const int* row = edges;          // edge_index[0]
    const int* col = edges + NEDGE;  // edge_index[1]
    float* outf = (float*)d_out;

    char* ws = (char*)d_ws;
    size_t p = 0;
    auto alloc = [&](size_t bytes) {
        void* r = ws + p;
        p += (bytes + 255) & ~(size_t)255;
        return r;
    };
    int* bcur16 = (int*)alloc((size_t)NBPAD * 16 * 4);
    float* dis = (float*)alloc((size_t)N_NODES * 4);
    int2* off2 = (int2*)alloc((size_t)N_NODES * 8);
    unsigned* ewf = (unsigned*)alloc((size_t)NBUCKET * ECAP * 4);   // 25.2 MB
    char* g0 = (char*)alloc((size_t)(N_NODES + 1) * D * 2);         // +1 zero row
    // bin (21.0 MB) dead after sortpass2; g1 (19.2 MB) first written after -> alias
    char* region = (char*)alloc((size_t)NBUCKET * BINCAP * 4);      // 21.0 MB
    unsigned* bin = (unsigned*)region;
    char* g1 = region;
    char* g2 = (char*)alloc((size_t)(N_NODES + 1) * D * 2);

    binit<<<(NBPAD + 255) / 256, 256, 0, stream>>>(bcur16);
    binpass2<<<NBIN_BLOCKS, 256, 0, stream>>>(row, col, bcur16, bin);
    sortpass2<<<NBUCKET, 256, 0, stream>>>(bin, bcur16, (const float4*)x, dis, off2,
                                           ewf, (uint2*)g0);
    // zero the dummy row in each g table (g1 after bin is dead)
    (void)hipMemsetAsync(g0 + (size_t)ZROW * 128, 0, 128, stream);
    (void)hipMemsetAsync(g1 + (size_t)ZROW * 128, 0, 128, stream);
    (void)hipMemsetAsync(g2 + (size_t)ZROW * 128, 0, 128, stream);

    const float alpha = 1.0f / (1.0f + NUM_LAYERS);
    int grid = (N_NODES / 2 * 64) / 256;  // 2 nodes per wave -> 18750 blocks
    layer8<false><<<grid, 256, 0, stream>>>(g0, off2, ewf, dis,
                                            g1, nullptr, nullptr, nullptr, alpha);
    layer8<false><<<grid, 256, 0, stream>>>(g1, off2, ewf, dis,
                                            g2, nullptr, nullptr, nullptr, alpha);
    layer8<true><<<grid, 256, 0, stream>>>(g2, off2, ewf, dis,
                                           nullptr, g1, g2, outf, alpha);
}

// Round 14
// 362.759 us; speedup vs baseline: 1.0013x; 1.0013x over previous
//
#include <hip/hip_runtime.h>
#include <hip/hip_fp16.h>
#include <math.h>

#define N_NODES 150000
#define D 64
#define NEDGE 4800000
#define NUM_LAYERS 3

#define BSHIFT 8
#define NBUCKET 586      // ceil(150000/256)
#define NBPAD 768        // 3*256 padded scan width
#define BINTILE 8192
#define NBIN_BLOCKS 586  // ceil(NEDGE/BINTILE)
#define BINCAP 8960      // fixed bin bucket capacity: mean 8192 + 8.5 sigma(90)
#define ECAP 10752       // fixed ewf bucket capacity: BINCAP + 256*7 pad bound
#define SCAP 9216        // sortpass2 LDS staging (len <= BINCAP < SCAP)
#define ZROW 150000u     // dummy src pointing at a zeroed row

typedef float vf4 __attribute__((ext_vector_type(4)));
typedef unsigned vu4 __attribute__((ext_vector_type(4)));

// ---- init fixed bucket cursors ----
__global__ void binit(int* __restrict__ bcur16) {
    int i = blockIdx.x * blockDim.x + threadIdx.x;
    if (i < NBPAD) bcur16[i * 16] = i * BINCAP;
}

// ---- pass 1: bucket-sort edges; LDS-staged records, per-thread ordered run write-out ----
__global__ void __launch_bounds__(256) binpass2(const int* __restrict__ row,
                                                const int* __restrict__ col,
                                                int* __restrict__ bcur16,
                                                unsigned* __restrict__ bin) {
    __shared__ unsigned srec[BINTILE];  // 32 KB, bucket-sorted records
    __shared__ int hist[NBPAD];
    __shared__ int lscan[NBPAD];
    __shared__ int lcur[NBPAD];
    __shared__ int gbase[NBPAD];
    __shared__ int tsum[256];
    int t = threadIdx.x;
    int base = blockIdx.x * BINTILE;
    int n = NEDGE - base;
    if (n > BINTILE) n = BINTILE;
    for (int i = t; i < NBPAD; i += 256) hist[i] = 0;
    __syncthreads();
    for (int i = t; i < n; i += 256)
        atomicAdd(&hist[col[base + i] >> BSHIFT], 1);
    __syncthreads();
    int b0 = t * 3;
    int l0 = hist[b0], l1 = hist[b0 + 1], l2 = hist[b0 + 2];
    tsum[t] = l0 + l1 + l2;
    __syncthreads();
    for (int ofs = 1; ofs < 256; ofs <<= 1) {
        int xv = (t >= ofs) ? tsum[t - ofs] : 0;
        __syncthreads();
        tsum[t] += xv;
        __syncthreads();
    }
    int run = (t > 0) ? tsum[t - 1] : 0;
    lscan[b0] = run; lcur[b0] = run;
    lscan[b0 + 1] = run + l0; lcur[b0 + 1] = run + l0;
    lscan[b0 + 2] = run + l0 + l1; lcur[b0 + 2] = run + l0 + l1;
    gbase[b0]     = l0 ? atomicAdd(&bcur16[b0 * 16], l0) : 0;
    gbase[b0 + 1] = l1 ? atomicAdd(&bcur16[(b0 + 1) * 16], l1) : 0;
    gbase[b0 + 2] = l2 ? atomicAdd(&bcur16[(b0 + 2) * 16], l2) : 0;
    __syncthreads();
    // stage records bucket-sorted in LDS (second global read of col)
    for (int i = t; i < n; i += 256) {
        int c = col[base + i];
        int r = row[base + i];
        int b = c >> BSHIFT;
        int pos = atomicAdd(&lcur[b], 1);
        srec[pos] = (unsigned)r | ((unsigned)(c & 255) << 18);
    }
    __syncthreads();
    // write-out: thread t copies its 3 buckets' runs contiguously
#pragma unroll
    for (int k = 0; k < 3; k++) {
        int b = b0 + k;
        int s = lscan[b], e2 = lcur[b], gb = gbase[b];
        for (int j = s; j < e2; j++) bin[gb + (j - s)] = srec[j];
    }
}

// ---- pass 2: within-bucket node sort + deg/dis/off2 + pad-to-8 lists + fused cvt ----
__global__ void __launch_bounds__(256) sortpass2(const unsigned* __restrict__ bin,
                                                 const int* __restrict__ bcur16,
                                                 const float4* __restrict__ x4,
                                                 float* __restrict__ dis,
                                                 int2* __restrict__ off2,
                                                 unsigned* __restrict__ ewf,
                                                 uint2* __restrict__ g0) {
    __shared__ unsigned srec[SCAP];
    __shared__ int hist[256];
    __shared__ int sc[256];
    __shared__ int ncur[256];
    __shared__ float sdis[256];
    int b = blockIdx.x, t = threadIdx.x;
    int s = b * BINCAP;
    int e = bcur16[b * 16];
    int len = e - s;
    int nst = len < SCAP ? len : SCAP;  // always fits (len <= BINCAP)
    for (int i = t; i < nst; i += 256) srec[i] = bin[s + i];
    hist[t] = 0;
    __syncthreads();
    for (int i = t; i < nst; i += 256)
        atomicAdd(&hist[srec[i] >> 18], 1);
    for (int i = nst + t; i < len; i += 256)
        atomicAdd(&hist[bin[s + i] >> 18], 1);
    __syncthreads();
    int val = hist[t];
    int lp = (val + 7) & ~7;  // padded list length (multiple of 8)
    sc[t] = lp;
    __syncthreads();
    for (int ofs = 1; ofs < 256; ofs <<= 1) {
        int xv = (t >= ofs) ? sc[t - ofs] : 0;
        __syncthreads();
        sc[t] += xv;
        __syncthreads();
    }
    int ex = sc[t] - lp;  // exclusive scan of padded lengths
    ncur[t] = ex;
    int ebase = b * ECAP;
    int node = (b << BSHIFT) + t;
    float w = (val > 0) ? (1.0f / sqrtf((float)val)) : 0.0f;
    if (node < N_NODES) {
        dis[node] = w;
        off2[node] = make_int2(ebase + ex, ebase + ex + lp);
    }
    sdis[t] = w;
    __syncthreads();
    for (int i = t; i < nst; i += 256) {
        unsigned rec = srec[i];
        int c = (int)(rec >> 18);
        int pos = ebase + atomicAdd(&ncur[c], 1);
        ewf[pos] = rec & 0x3FFFFu;
    }
    for (int i = nst + t; i < len; i += 256) {
        unsigned rec = bin[s + i];
        int c = (int)(rec >> 18);
        int pos = ebase + atomicAdd(&ncur[c], 1);
        ewf[pos] = rec & 0x3FFFFu;
    }
    // pad fill: disjoint addresses from scatter -> no sync needed
    for (int j = val; j < lp; ++j) ewf[ebase + ex + j] = ZROW;
    // fused cvt: g0 = dis * x (fp16) for this block's 256 nodes (coalesced)
    int gb16 = (b << 8) * 16;
    for (int i = t; i < 4096; i += 256) {
        int nl = i >> 4;
        int gnode = (b << 8) + nl;
        if (gnode >= N_NODES) continue;
        float wv = sdis[nl];
        float4 v = x4[gb16 + i];
        __half2 ha = __floats2half2_rn(wv * v.x, wv * v.y);
        __half2 hb = __floats2half2_rn(wv * v.z, wv * v.w);
        uint2 r;
        r.x = *reinterpret_cast<unsigned*>(&ha);
        r.y = *reinterpret_cast<unsigned*>(&hb);
        g0[gb16 + i] = r;
    }
}

// ---- propagation layer: wave64 handles TWO nodes (2 independent gather chains) ----
// R11 structure (proven 85.5us); ewf read with nontemporal hint (single-use stream).
template <bool FINAL>
__global__ void layer8(const char* __restrict__ hbase, const int2* __restrict__ off2,
                       const unsigned* __restrict__ ewf, const float* __restrict__ dis,
                       char* __restrict__ hout, const char* __restrict__ hA,
                       const char* __restrict__ hB, float* __restrict__ outf,
                       float alpha) {
    int wv = (blockIdx.x * blockDim.x + threadIdx.x) >> 6;
    int wid0 = wv << 1;
    if (wid0 >= N_NODES) return;
    int wid1 = wid0 | 1;  // N_NODES even -> always valid
    unsigned lane = threadIdx.x & 63u;
    unsigned g = lane >> 3;
    unsigned sub16 = (lane & 7u) << 4;
    int2 se0 = off2[wid0];
    int2 se1 = off2[wid1];
    int L0 = (se0.y - se0.x) >> 3;
    int L1 = (se1.y - se1.x) >> 3;
    int p0 = se0.x + (int)g * L0;
    int p1 = se1.x + (int)g * L1;

    float a0 = 0.f, a1 = 0.f, a2 = 0.f, a3 = 0.f;
    float a4 = 0.f, a5 = 0.f, a6 = 0.f, a7 = 0.f;
    float b0 = 0.f, b1 = 0.f, b2 = 0.f, b3 = 0.f;
    float b4 = 0.f, b5 = 0.f, b6 = 0.f, b7 = 0.f;

    auto ROW = [&](unsigned r) {
        return *reinterpret_cast<const uint4*>(hbase + ((r << 7) | sub16));
    };
    auto EW = [&](int idx) { return __builtin_nontemporal_load(&ewf[idx]); };
#define ACCD(d, aL, aH)                                                          \
    asm("v_fma_mix_f32 %0, %2, 1.0, %0 op_sel:[0,0,0] op_sel_hi:[1,0,0]\n\t"     \
        "v_fma_mix_f32 %1, %2, 1.0, %1 op_sel:[1,0,0] op_sel_hi:[1,0,0]"         \
        : "+v"(aL), "+v"(aH) : "v"(d))
#define ACCVA(v)               \
    do {                       \
        ACCD((v).x, a0, a1);   \
        ACCD((v).y, a2, a3);   \
        ACCD((v).z, a4, a5);   \
        ACCD((v).w, a6, a7);   \
    } while (0)
#define ACCVB(v)               \
    do {                       \
        ACCD((v).x, b0, b1);   \
        ACCD((v).y, b2, b3);   \
        ACCD((v).z, b4, b5);   \
        ACCD((v).w, b6, b7);   \
    } while (0)

    int m = (L0 < L1) ? L0 : L1;
    int k = 0;
    for (; k + 1 < m; k += 2) {  // 4 gathers in flight across 2 chains
        unsigned r00 = EW(p0 + k), r01 = EW(p0 + k + 1);
        unsigned r10 = EW(p1 + k), r11 = EW(p1 + k + 1);
        uint4 v00 = ROW(r00), v10 = ROW(r10), v01 = ROW(r01), v11 = ROW(r11);
        ACCVA(v00); ACCVB(v10); ACCVA(v01); ACCVB(v11);
    }
    int k0 = k, k1 = k;
    for (; k0 < L0; ++k0) { uint4 v = ROW(EW(p0 + k0)); ACCVA(v); }
    for (; k1 < L1; ++k1) { uint4 v = ROW(EW(p1 + k1)); ACCVB(v); }
#undef ACCVA
#undef ACCVB
#undef ACCD

    // reduce the 8 lane-groups (lanes sharing sub)
#pragma unroll
    for (int mm = 8; mm <= 32; mm <<= 1) {
        a0 += __shfl_xor(a0, mm, 64); a1 += __shfl_xor(a1, mm, 64);
        a2 += __shfl_xor(a2, mm, 64); a3 += __shfl_xor(a3, mm, 64);
        a4 += __shfl_xor(a4, mm, 64); a5 += __shfl_xor(a5, mm, 64);
        a6 += __shfl_xor(a6, mm, 64); a7 += __shfl_xor(a7, mm, 64);
        b0 += __shfl_xor(b0, mm, 64); b1 += __shfl_xor(b1, mm, 64);
        b2 += __shfl_xor(b2, mm, 64); b3 += __shfl_xor(b3, mm, 64);
        b4 += __shfl_xor(b4, mm, 64); b5 += __shfl_xor(b5, mm, 64);
        b6 += __shfl_xor(b6, mm, 64); b7 += __shfl_xor(b7, mm, 64);
    }

    if (g >= 2) return;
    int wid = (g == 0) ? wid0 : wid1;
    float s0 = g ? b0 : a0, s1 = g ? b1 : a1, s2 = g ? b2 : a2, s3 = g ? b3 : a3;
    float s4 = g ? b4 : a4, s5 = g ? b5 : a5, s6 = g ? b6 : a6, s7 = g ? b7 : a7;
    float w = dis[wid];
    unsigned ro = ((unsigned)wid << 7) | sub16;
    if (FINAL) {
        float inv = (w > 0.f) ? 1.0f / w : 0.f;
        uint4 a = *reinterpret_cast<const uint4*>(hA + ro);
        uint4 b = *reinterpret_cast<const uint4*>(hB + ro);
        const __half2* pa = reinterpret_cast<const __half2*>(&a);
        const __half2* pb = reinterpret_cast<const __half2*>(&b);
        float2 f0 = __half22float2(pa[0]), f1 = __half22float2(pa[1]);
        float2 f2 = __half22float2(pa[2]), f3 = __half22float2(pa[3]);
        float2 q0 = __half22float2(pb[0]), q1 = __half22float2(pb[1]);
        float2 q2 = __half22float2(pb[2]), q3 = __half22float2(pb[3]);
        vf4 o0 = {alpha * (inv * (f0.x + q0.x) + w * s0),
                  alpha * (inv * (f0.y + q0.y) + w * s1),
                  alpha * (inv * (f1.x + q1.x) + w * s2),
                  alpha * (inv * (f1.y + q1.y) + w * s3)};
        vf4 o1 = {alpha * (inv * (f2.x + q2.x) + w * s4),
                  alpha * (inv * (f2.y + q2.y) + w * s5),
                  alpha * (inv * (f3.x + q3.x) + w * s6),
                  alpha * (inv * (f3.y + q3.y) + w * s7)};
        unsigned sub = (lane & 7u);
        vf4* dst = reinterpret_cast<vf4*>(outf + (size_t)wid * 64 + sub * 8);
        __builtin_nontemporal_store(o0, dst);
        __builtin_nontemporal_store(o1, dst + 1);
    } else {
        float w2 = w * w;  // g_next = dis^2 * S
        __half2 q0 = __floats2half2_rn(w2 * s0, w2 * s1);
        __half2 q1 = __floats2half2_rn(w2 * s2, w2 * s3);
        __half2 q2 = __floats2half2_rn(w2 * s4, w2 * s5);
        __half2 q3 = __floats2half2_rn(w2 * s6, w2 * s7);
        vu4 st;
        st.x = *reinterpret_cast<unsigned*>(&q0);
        st.y = *reinterpret_cast<unsigned*>(&q1);
        st.z = *reinterpret_cast<unsigned*>(&q2);
        st.w = *reinterpret_cast<unsigned*>(&q3);
        __builtin_nontemporal_store(st, reinterpret_cast<vu4*>(hout + ro));
    }
}

extern "C" void kernel_launch(void* const* d_in, const int* in_sizes, int n_in,
                              void* d_out, int out_size, void* d_ws, size_t ws_size,
                              hipStream_t stream) {
    const float* x = (const float*)d_in[0];
    const int* edges = (const int*)d_in[1];
    const int* row = edges;          // edge_index[0]
    const int* col = edges + NEDGE;  // edge_index[1]
    float* outf = (float*)d_out;

    char* ws = (char*)d_ws;
    size_t p = 0;
    auto alloc = [&](size_t bytes) {
        void* r = ws + p;
        p += (bytes + 255) & ~(size_t)255;
        return r;
    };
    int* bcur16 = (int*)alloc((size_t)NBPAD * 16 * 4);
    float* dis = (float*)alloc((size_t)N_NODES * 4);
    int2* off2 = (int2*)alloc((size_t)N_NODES * 8);
    unsigned* ewf = (unsigned*)alloc((size_t)NBUCKET * ECAP * 4);   // 25.2 MB
    char* g0 = (char*)alloc((size_t)(N_NODES + 1) * D * 2);         // +1 zero row
    // bin (21.0 MB) dead after sortpass2; g1 (19.2 MB) first written after -> alias
    char* region = (char*)alloc((size_t)NBUCKET * BINCAP * 4);      // 21.0 MB
    unsigned* bin = (unsigned*)region;
    char* g1 = region;
    char* g2 = (char*)alloc((size_t)(N_NODES + 1) * D * 2);

    binit<<<(NBPAD + 255) / 256, 256, 0, stream>>>(bcur16);
    binpass2<<<NBIN_BLOCKS, 256, 0, stream>>>(row, col, bcur16, bin);
    sortpass2<<<NBUCKET, 256, 0, stream>>>(bin, bcur16, (const float4*)x, dis, off2,
                                           ewf, (uint2*)g0);
    // zero the dummy row in each g table (g1 after bin is dead)
    (void)hipMemsetAsync(g0 + (size_t)ZROW * 128, 0, 128, stream);
    (void)hipMemsetAsync(g1 + (size_t)ZROW * 128, 0, 128, stream);
    (void)hipMemsetAsync(g2 + (size_t)ZROW * 128, 0, 128, stream);

    const float alpha = 1.0f / (1.0f + NUM_LAYERS);
    int grid = (N_NODES / 2 * 64) / 256;  // 2 nodes per wave -> 18750 blocks
    layer8<false><<<grid, 256, 0, stream>>>(g0, off2, ewf, dis,
                                            g1, nullptr, nullptr, nullptr, alpha);
    layer8<false><<<grid, 256, 0, stream>>>(g1, off2, ewf, dis,
                                            g2, nullptr, nullptr, nullptr, alpha);
    layer8<true><<<grid, 256, 0, stream>>>(g2, off2, ewf, dis,
                                           nullptr, g1, g2, outf, alpha);
}

// Round 15
// 344.129 us; speedup vs baseline: 1.0555x; 1.0541x over previous
//
#include <hip/hip_runtime.h>
#include <hip/hip_fp16.h>
#include <math.h>

#define N_NODES 150000
#define D 64
#define NEDGE 4800000
#define NUM_LAYERS 3

#define BSHIFT 8
#define NBUCKET 586      // ceil(150000/256)
#define NBPAD 768        // 3*256 padded scan width
#define BINTILE 8192
#define NBIN_BLOCKS 586  // ceil(NEDGE/BINTILE)
#define BINCAP 8960      // fixed bin bucket capacity: mean 8192 + 8.5 sigma(90)
#define ECAP 10752       // fixed ewf bucket capacity: BINCAP + 256*7 pad bound
#define SCAP 9216        // sortpass2 LDS staging (len <= BINCAP < SCAP)
#define ZROW 150000u     // dummy src pointing at a zeroed row

typedef float vf4 __attribute__((ext_vector_type(4)));
typedef unsigned vu4 __attribute__((ext_vector_type(4)));

// ---- init fixed bucket cursors ----
__global__ void binit(int* __restrict__ bcur16) {
    int i = blockIdx.x * blockDim.x + threadIdx.x;
    if (i < NBPAD) bcur16[i * 16] = i * BINCAP;
}

// ---- pass 1: bucket-sort edges; LDS-staged records, per-thread ordered run write-out ----
__global__ void __launch_bounds__(256) binpass2(const int* __restrict__ row,
                                                const int* __restrict__ col,
                                                int* __restrict__ bcur16,
                                                unsigned* __restrict__ bin) {
    __shared__ unsigned srec[BINTILE];  // 32 KB, bucket-sorted records
    __shared__ int hist[NBPAD];
    __shared__ int lscan[NBPAD];
    __shared__ int lcur[NBPAD];
    __shared__ int gbase[NBPAD];
    __shared__ int tsum[256];
    int t = threadIdx.x;
    int base = blockIdx.x * BINTILE;
    int n = NEDGE - base;
    if (n > BINTILE) n = BINTILE;
    for (int i = t; i < NBPAD; i += 256) hist[i] = 0;
    __syncthreads();
    for (int i = t; i < n; i += 256)
        atomicAdd(&hist[col[base + i] >> BSHIFT], 1);
    __syncthreads();
    int b0 = t * 3;
    int l0 = hist[b0], l1 = hist[b0 + 1], l2 = hist[b0 + 2];
    tsum[t] = l0 + l1 + l2;
    __syncthreads();
    for (int ofs = 1; ofs < 256; ofs <<= 1) {
        int xv = (t >= ofs) ? tsum[t - ofs] : 0;
        __syncthreads();
        tsum[t] += xv;
        __syncthreads();
    }
    int run = (t > 0) ? tsum[t - 1] : 0;
    lscan[b0] = run; lcur[b0] = run;
    lscan[b0 + 1] = run + l0; lcur[b0 + 1] = run + l0;
    lscan[b0 + 2] = run + l0 + l1; lcur[b0 + 2] = run + l0 + l1;
    gbase[b0]     = l0 ? atomicAdd(&bcur16[b0 * 16], l0) : 0;
    gbase[b0 + 1] = l1 ? atomicAdd(&bcur16[(b0 + 1) * 16], l1) : 0;
    gbase[b0 + 2] = l2 ? atomicAdd(&bcur16[(b0 + 2) * 16], l2) : 0;
    __syncthreads();
    // stage records bucket-sorted in LDS (second global read of col)
    for (int i = t; i < n; i += 256) {
        int c = col[base + i];
        int r = row[base + i];
        int b = c >> BSHIFT;
        int pos = atomicAdd(&lcur[b], 1);
        srec[pos] = (unsigned)r | ((unsigned)(c & 255) << 18);
    }
    __syncthreads();
    // write-out: thread t copies its 3 buckets' runs contiguously
#pragma unroll
    for (int k = 0; k < 3; k++) {
        int b = b0 + k;
        int s = lscan[b], e2 = lcur[b], gb = gbase[b];
        for (int j = s; j < e2; j++) bin[gb + (j - s)] = srec[j];
    }
}

// ---- pass 2: within-bucket node sort + deg/dis/off2 + pad-to-8 lists + fused cvt ----
__global__ void __launch_bounds__(256) sortpass2(const unsigned* __restrict__ bin,
                                                 const int* __restrict__ bcur16,
                                                 const float4* __restrict__ x4,
                                                 float* __restrict__ dis,
                                                 int2* __restrict__ off2,
                                                 unsigned* __restrict__ ewf,
                                                 uint2* __restrict__ g0) {
    __shared__ unsigned srec[SCAP];
    __shared__ int hist[256];
    __shared__ int sc[256];
    __shared__ int ncur[256];
    __shared__ float sdis[256];
    int b = blockIdx.x, t = threadIdx.x;
    int s = b * BINCAP;
    int e = bcur16[b * 16];
    int len = e - s;
    int nst = len < SCAP ? len : SCAP;  // always fits (len <= BINCAP)
    for (int i = t; i < nst; i += 256) srec[i] = bin[s + i];
    hist[t] = 0;
    __syncthreads();
    for (int i = t; i < nst; i += 256)
        atomicAdd(&hist[srec[i] >> 18], 1);
    for (int i = nst + t; i < len; i += 256)
        atomicAdd(&hist[bin[s + i] >> 18], 1);
    __syncthreads();
    int val = hist[t];
    int lp = (val + 7) & ~7;  // padded list length (multiple of 8)
    sc[t] = lp;
    __syncthreads();
    for (int ofs = 1; ofs < 256; ofs <<= 1) {
        int xv = (t >= ofs) ? sc[t - ofs] : 0;
        __syncthreads();
        sc[t] += xv;
        __syncthreads();
    }
    int ex = sc[t] - lp;  // exclusive scan of padded lengths
    ncur[t] = ex;
    int ebase = b * ECAP;
    int node = (b << BSHIFT) + t;
    float w = (val > 0) ? (1.0f / sqrtf((float)val)) : 0.0f;
    if (node < N_NODES) {
        dis[node] = w;
        off2[node] = make_int2(ebase + ex, ebase + ex + lp);
    }
    sdis[t] = w;
    __syncthreads();
    for (int i = t; i < nst; i += 256) {
        unsigned rec = srec[i];
        int c = (int)(rec >> 18);
        int pos = ebase + atomicAdd(&ncur[c], 1);
        ewf[pos] = rec & 0x3FFFFu;
    }
    for (int i = nst + t; i < len; i += 256) {
        unsigned rec = bin[s + i];
        int c = (int)(rec >> 18);
        int pos = ebase + atomicAdd(&ncur[c], 1);
        ewf[pos] = rec & 0x3FFFFu;
    }
    // pad fill: disjoint addresses from scatter -> no sync needed
    for (int j = val; j < lp; ++j) ewf[ebase + ex + j] = ZROW;
    // fused cvt: g0 = dis * x (fp16) for this block's 256 nodes (coalesced)
    int gb16 = (b << 8) * 16;
    for (int i = t; i < 4096; i += 256) {
        int nl = i >> 4;
        int gnode = (b << 8) + nl;
        if (gnode >= N_NODES) continue;
        float wv = sdis[nl];
        float4 v = x4[gb16 + i];
        __half2 ha = __floats2half2_rn(wv * v.x, wv * v.y);
        __half2 hb = __floats2half2_rn(wv * v.z, wv * v.w);
        uint2 r;
        r.x = *reinterpret_cast<unsigned*>(&ha);
        r.y = *reinterpret_cast<unsigned*>(&hb);
        g0[gb16 + i] = r;
    }
}

// ---- propagation layer: wave64 handles TWO nodes (2 independent gather chains) ----
// Exact R11 structure (measured 85.5us/layer, 344us total) — the proven optimum.
template <bool FINAL>
__global__ void layer8(const char* __restrict__ hbase, const int2* __restrict__ off2,
                       const unsigned* __restrict__ ewf, const float* __restrict__ dis,
                       char* __restrict__ hout, const char* __restrict__ hA,
                       const char* __restrict__ hB, float* __restrict__ outf,
                       float alpha) {
    int wv = (blockIdx.x * blockDim.x + threadIdx.x) >> 6;
    int wid0 = wv << 1;
    if (wid0 >= N_NODES) return;
    int wid1 = wid0 | 1;  // N_NODES even -> always valid
    unsigned lane = threadIdx.x & 63u;
    unsigned g = lane >> 3;
    unsigned sub16 = (lane & 7u) << 4;
    int2 se0 = off2[wid0];
    int2 se1 = off2[wid1];
    int L0 = (se0.y - se0.x) >> 3;
    int L1 = (se1.y - se1.x) >> 3;
    int p0 = se0.x + (int)g * L0;
    int p1 = se1.x + (int)g * L1;

    float a0 = 0.f, a1 = 0.f, a2 = 0.f, a3 = 0.f;
    float a4 = 0.f, a5 = 0.f, a6 = 0.f, a7 = 0.f;
    float b0 = 0.f, b1 = 0.f, b2 = 0.f, b3 = 0.f;
    float b4 = 0.f, b5 = 0.f, b6 = 0.f, b7 = 0.f;

    auto ROW = [&](unsigned r) {
        return *reinterpret_cast<const uint4*>(hbase + ((r << 7) | sub16));
    };
#define ACCD(d, aL, aH)                                                          \
    asm("v_fma_mix_f32 %0, %2, 1.0, %0 op_sel:[0,0,0] op_sel_hi:[1,0,0]\n\t"     \
        "v_fma_mix_f32 %1, %2, 1.0, %1 op_sel:[1,0,0] op_sel_hi:[1,0,0]"         \
        : "+v"(aL), "+v"(aH) : "v"(d))
#define ACCVA(v)               \
    do {                       \
        ACCD((v).x, a0, a1);   \
        ACCD((v).y, a2, a3);   \
        ACCD((v).z, a4, a5);   \
        ACCD((v).w, a6, a7);   \
    } while (0)
#define ACCVB(v)               \
    do {                       \
        ACCD((v).x, b0, b1);   \
        ACCD((v).y, b2, b3);   \
        ACCD((v).z, b4, b5);   \
        ACCD((v).w, b6, b7);   \
    } while (0)

    int m = (L0 < L1) ? L0 : L1;
    int k = 0;
    for (; k + 1 < m; k += 2) {  // 4 gathers in flight across 2 chains
        unsigned r00 = ewf[p0 + k], r01 = ewf[p0 + k + 1];
        unsigned r10 = ewf[p1 + k], r11 = ewf[p1 + k + 1];
        uint4 v00 = ROW(r00), v10 = ROW(r10), v01 = ROW(r01), v11 = ROW(r11);
        ACCVA(v00); ACCVB(v10); ACCVA(v01); ACCVB(v11);
    }
    int k0 = k, k1 = k;
    for (; k0 < L0; ++k0) { uint4 v = ROW(ewf[p0 + k0]); ACCVA(v); }
    for (; k1 < L1; ++k1) { uint4 v = ROW(ewf[p1 + k1]); ACCVB(v); }
#undef ACCVA
#undef ACCVB
#undef ACCD

    // reduce the 8 lane-groups (lanes sharing sub)
#pragma unroll
    for (int mm = 8; mm <= 32; mm <<= 1) {
        a0 += __shfl_xor(a0, mm, 64); a1 += __shfl_xor(a1, mm, 64);
        a2 += __shfl_xor(a2, mm, 64); a3 += __shfl_xor(a3, mm, 64);
        a4 += __shfl_xor(a4, mm, 64); a5 += __shfl_xor(a5, mm, 64);
        a6 += __shfl_xor(a6, mm, 64); a7 += __shfl_xor(a7, mm, 64);
        b0 += __shfl_xor(b0, mm, 64); b1 += __shfl_xor(b1, mm, 64);
        b2 += __shfl_xor(b2, mm, 64); b3 += __shfl_xor(b3, mm, 64);
        b4 += __shfl_xor(b4, mm, 64); b5 += __shfl_xor(b5, mm, 64);
        b6 += __shfl_xor(b6, mm, 64); b7 += __shfl_xor(b7, mm, 64);
    }

    if (g >= 2) return;
    int wid = (g == 0) ? wid0 : wid1;
    float s0 = g ? b0 : a0, s1 = g ? b1 : a1, s2 = g ? b2 : a2, s3 = g ? b3 : a3;
    float s4 = g ? b4 : a4, s5 = g ? b5 : a5, s6 = g ? b6 : a6, s7 = g ? b7 : a7;
    float w = dis[wid];
    unsigned ro = ((unsigned)wid << 7) | sub16;
    if (FINAL) {
        float inv = (w > 0.f) ? 1.0f / w : 0.f;
        uint4 a = *reinterpret_cast<const uint4*>(hA + ro);
        uint4 b = *reinterpret_cast<const uint4*>(hB + ro);
        const __half2* pa = reinterpret_cast<const __half2*>(&a);
        const __half2* pb = reinterpret_cast<const __half2*>(&b);
        float2 f0 = __half22float2(pa[0]), f1 = __half22float2(pa[1]);
        float2 f2 = __half22float2(pa[2]), f3 = __half22float2(pa[3]);
        float2 q0 = __half22float2(pb[0]), q1 = __half22float2(pb[1]);
        float2 q2 = __half22float2(pb[2]), q3 = __half22float2(pb[3]);
        vf4 o0 = {alpha * (inv * (f0.x + q0.x) + w * s0),
                  alpha * (inv * (f0.y + q0.y) + w * s1),
                  alpha * (inv * (f1.x + q1.x) + w * s2),
                  alpha * (inv * (f1.y + q1.y) + w * s3)};
        vf4 o1 = {alpha * (inv * (f2.x + q2.x) + w * s4),
                  alpha * (inv * (f2.y + q2.y) + w * s5),
                  alpha * (inv * (f3.x + q3.x) + w * s6),
                  alpha * (inv * (f3.y + q3.y) + w * s7)};
        unsigned sub = (lane & 7u);
        vf4* dst = reinterpret_cast<vf4*>(outf + (size_t)wid * 64 + sub * 8);
        __builtin_nontemporal_store(o0, dst);
        __builtin_nontemporal_store(o1, dst + 1);
    } else {
        float w2 = w * w;  // g_next = dis^2 * S
        __half2 q0 = __floats2half2_rn(w2 * s0, w2 * s1);
        __half2 q1 = __floats2half2_rn(w2 * s2, w2 * s3);
        __half2 q2 = __floats2half2_rn(w2 * s4, w2 * s5);
        __half2 q3 = __floats2half2_rn(w2 * s6, w2 * s7);
        vu4 st;
        st.x = *reinterpret_cast<unsigned*>(&q0);
        st.y = *reinterpret_cast<unsigned*>(&q1);
        st.z = *reinterpret_cast<unsigned*>(&q2);
        st.w = *reinterpret_cast<unsigned*>(&q3);
        __builtin_nontemporal_store(st, reinterpret_cast<vu4*>(hout + ro));
    }
}

extern "C" void kernel_launch(void* const* d_in, const int* in_sizes, int n_in,
                              void* d_out, int out_size, void* d_ws, size_t ws_size,
                              hipStream_t stream) {
    const float* x = (const float*)d_in[0];
    const int* edges = (const int*)d_in[1];
    const int* row = edges;          // edge_index[0]
    const int* col = edges + NEDGE;  // edge_index[1]
    float* outf = (float*)d_out;

    char* ws = (char*)d_ws;
    size_t p = 0;
    auto alloc = [&](size_t bytes) {
        void* r = ws + p;
        p += (bytes + 255) & ~(size_t)255;
        return r;
    };
    int* bcur16 = (int*)alloc((size_t)NBPAD * 16 * 4);
    float* dis = (float*)alloc((size_t)N_NODES * 4);
    int2* off2 = (int2*)alloc((size_t)N_NODES * 8);
    unsigned* ewf = (unsigned*)alloc((size_t)NBUCKET * ECAP * 4);   // 25.2 MB
    char* g0 = (char*)alloc((size_t)(N_NODES + 1) * D * 2);         // +1 zero row
    // bin (21.0 MB) dead after sortpass2; g1 (19.2 MB) first written after -> alias
    char* region = (char*)alloc((size_t)NBUCKET * BINCAP * 4);      // 21.0 MB
    unsigned* bin = (unsigned*)region;
    char* g1 = region;
    char* g2 = (char*)alloc((size_t)(N_NODES + 1) * D * 2);

    binit<<<(NBPAD + 255) / 256, 256, 0, stream>>>(bcur16);
    binpass2<<<NBIN_BLOCKS, 256, 0, stream>>>(row, col, bcur16, bin);
    sortpass2<<<NBUCKET, 256, 0, stream>>>(bin, bcur16, (const float4*)x, dis, off2,
                                           ewf, (uint2*)g0);
    // zero the dummy row in each g table (g1 after bin is dead)
    (void)hipMemsetAsync(g0 + (size_t)ZROW * 128, 0, 128, stream);
    (void)hipMemsetAsync(g1 + (size_t)ZROW * 128, 0, 128, stream);
    (void)hipMemsetAsync(g2 + (size_t)ZROW * 128, 0, 128, stream);

    const float alpha = 1.0f / (1.0f + NUM_LAYERS);
    int grid = (N_NODES / 2 * 64) / 256;  // 2 nodes per wave -> 18750 blocks
    layer8<false><<<grid, 256, 0, stream>>>(g0, off2, ewf, dis,
                                            g1, nullptr, nullptr, nullptr, alpha);
    layer8<false><<<grid, 256, 0, stream>>>(g1, off2, ewf, dis,
                                            g2, nullptr, nullptr, nullptr, alpha);
    layer8<true><<<grid, 256, 0, stream>>>(g2, off2, ewf, dis,
                                           nullptr, g1, g2, outf, alpha);
}